// Round 1
// baseline (396.073 us; speedup 1.0000x reference)
//
#include <hip/hip_runtime.h>
#include <stdint.h>

#define B_ 2
#define H_ 16
#define S_ 2048
#define D_ 128

typedef float f32x4 __attribute__((ext_vector_type(4)));
typedef short bf16x8 __attribute__((ext_vector_type(8)));

__device__ __forceinline__ unsigned short f2bf(float x){
  union { float f; uint32_t u; } c; c.f = x;
  uint32_t u = c.u;
  uint32_t r = (u + 0x7FFFu + ((u >> 16) & 1u)) >> 16;
  return (unsigned short)r;
}

// ---- prep: K fp32 -> bf16 (same layout) ----
__global__ void kconv_kernel(const float* __restrict__ k, unsigned short* __restrict__ KB){
  size_t i = (size_t)blockIdx.x * 256 + threadIdx.x;   // 2,097,152 float4s exactly
  f32x4 v = ((const f32x4*)k)[i];
  ushort4 o; o.x=f2bf(v.x); o.y=f2bf(v.y); o.z=f2bf(v.z); o.w=f2bf(v.w);
  ((ushort4*)KB)[i] = o;
}

// ---- prep: V fp32 [bh][t][d] -> VT bf16 [bh][d][t] ----
__global__ void vtrans_kernel(const float* __restrict__ v, unsigned short* __restrict__ VT){
  __shared__ float tile[64][72];
  int blk = blockIdx.x;            // 2048 = 32 bh * 32 ttile * 2 dtile
  int bh = blk >> 6;
  int ts = (blk >> 1) & 31;
  int dsec = blk & 1;
  int t0 = ts*64, d0 = dsec*64;
  const float* vb = v + ((size_t)bh*S_ + t0)*D_ + d0;
  int tid = threadIdx.x;
  #pragma unroll
  for (int i=0;i<4;++i){
    int fi = i*256 + tid;          // 1024 float4 per tile
    int r = fi >> 4;
    int c4 = (fi & 15) * 4;
    f32x4 val = *(const f32x4*)(vb + (size_t)r*D_ + c4);
    tile[r][c4+0]=val.x; tile[r][c4+1]=val.y; tile[r][c4+2]=val.z; tile[r][c4+3]=val.w;
  }
  __syncthreads();
  unsigned short* ob = VT + ((size_t)bh*D_ + d0)*S_ + t0;
  #pragma unroll
  for (int i=0;i<4;++i){
    int ui = i*256 + tid;          // 1024 ushort4 per tile
    int dr = ui >> 4;
    int tc = (ui & 15) * 4;
    ushort4 o;
    o.x = f2bf(tile[tc+0][dr]);
    o.y = f2bf(tile[tc+1][dr]);
    o.z = f2bf(tile[tc+2][dr]);
    o.w = f2bf(tile[tc+3][dr]);
    *(ushort4*)(ob + (size_t)dr*S_ + tc) = o;
  }
}

// ---- main fused kernel: stats (m,l) + W = mask@V, out = c*W ----
__launch_bounds__(256, 2)
__global__ void fused_kernel(const float* __restrict__ q,
                             const int* __restrict__ mask,
                             const unsigned short* __restrict__ KB,
                             const unsigned short* __restrict__ VT,
                             float* __restrict__ outp,
                             float* __restrict__ c_ws)
{
  __shared__ unsigned char Ksm[64*256];    // [t][128 bf16], row-XOR-swizzled
  __shared__ unsigned char Vsm[128*128];   // [d][64 bf16],  row-XOR-swizzled
  const int tid = threadIdx.x;
  const int lane = tid & 63;
  const int w = tid >> 6;
  const int l16 = lane & 15;
  const int lhi = lane >> 4;

  const int blk = blockIdx.x;
  const int bh = blk >> 4;
  const int qt = blk & 15;
  const int b = bh >> 4;
  const int s0 = qt * 128;
  const int rowbase = s0 + 32*w;

  const float QS = 1.4426950408889634f / 11.313708498984761f;  // log2(e)/TEMP
  const float MLOG2 = 1.4426950408889634e-9f;                  // 1e-9*log2(e)

  // Q fragments (2 rf x 4 ks), scaled into log2 domain
  bf16x8 qf[2][4];
  #pragma unroll
  for (int rf=0; rf<2; ++rf){
    const float* qp = q + ((size_t)bh*S_ + (rowbase + 16*rf + l16))*D_ + lhi*8;
    #pragma unroll
    for (int ks=0; ks<4; ++ks){
      f32x4 a0 = *(const f32x4*)(qp + 32*ks);
      f32x4 a1 = *(const f32x4*)(qp + 32*ks + 4);
      bf16x8 f;
      f[0]=(short)f2bf(a0.x*QS); f[1]=(short)f2bf(a0.y*QS);
      f[2]=(short)f2bf(a0.z*QS); f[3]=(short)f2bf(a0.w*QS);
      f[4]=(short)f2bf(a1.x*QS); f[5]=(short)f2bf(a1.y*QS);
      f[6]=(short)f2bf(a1.z*QS); f[7]=(short)f2bf(a1.w*QS);
      qf[rf][ks] = f;
    }
  }

  f32x4 Wacc[2][8];
  #pragma unroll
  for (int rf=0;rf<2;++rf)
    #pragma unroll
    for (int dc=0;dc<8;++dc){ f32x4 z = {0.f,0.f,0.f,0.f}; Wacc[rf][dc] = z; }
  float mrow[2][4], lrow[2][4];
  #pragma unroll
  for (int rf=0;rf<2;++rf)
    #pragma unroll
    for (int r=0;r<4;++r){ mrow[rf][r] = -1e30f; lrow[rf][r]=0.f; }

  const unsigned short* Kg = KB + (size_t)bh*S_*D_;
  const unsigned short* Vg = VT + (size_t)bh*D_*S_;
  const int* maskb = mask + (size_t)b*S_*S_;

  for (int it=0; it<32; ++it){
    const int t0 = it*64;
    __syncthreads();
    // stage K tile (64 rows x 256B) and VT tile (128 rows x 128B), swizzled
    {
      const unsigned char* src = (const unsigned char*)(Kg + (size_t)t0*D_);
      #pragma unroll
      for (int i=0;i<4;++i){
        int chunk = i*256 + tid;        // 1024 chunks of 16B
        int r = chunk >> 4;
        int cb = (chunk & 15) << 4;
        int4 val = *(const int4*)(src + (size_t)r*256 + cb);
        *(int4*)(Ksm + r*256 + (cb ^ ((r&7)<<4))) = val;
      }
      const unsigned char* vsrc = (const unsigned char*)(Vg + t0);
      #pragma unroll
      for (int i=0;i<4;++i){
        int chunk = i*256 + tid;        // 1024 chunks of 16B
        int r = chunk >> 3;             // 128 rows x 8 chunks
        int cb = (chunk & 7) << 4;
        int4 val = *(const int4*)(vsrc + (size_t)r*(S_*2) + cb);
        *(int4*)(Vsm + r*128 + (cb ^ ((r&7)<<4))) = val;
      }
    }
    __syncthreads();

    // QK^T -> S fragments (log2 domain)
    f32x4 Sacc[2][4];
    #pragma unroll
    for (int rf=0;rf<2;++rf)
      #pragma unroll
      for (int cf=0;cf<4;++cf){ f32x4 z = {0.f,0.f,0.f,0.f}; Sacc[rf][cf] = z; }
    #pragma unroll
    for (int cf=0; cf<4; ++cf){
      int t_l = 16*cf + l16;
      #pragma unroll
      for (int ks=0; ks<4; ++ks){
        int cb = 64*ks + lhi*16;
        bf16x8 bfr = *(const bf16x8*)(Ksm + t_l*256 + (cb ^ ((t_l&7)<<4)));
        Sacc[0][cf] = __builtin_amdgcn_mfma_f32_16x16x32_bf16(qf[0][ks], bfr, Sacc[0][cf], 0,0,0);
        Sacc[1][cf] = __builtin_amdgcn_mfma_f32_16x16x32_bf16(qf[1][ks], bfr, Sacc[1][cf], 0,0,0);
      }
    }

    // masking + online stats (per lane: 8 rows x 4 cols this tile)
    #pragma unroll
    for (int rf=0; rf<2; ++rf){
      #pragma unroll
      for (int reg=0; reg<4; ++reg){
        int srow = rowbase + 16*rf + 4*lhi + reg;
        const int* mp = maskb + (size_t)srow*S_ + t0 + l16;
        float x0 = mp[0]  ? MLOG2 : Sacc[rf][0][reg];
        float x1 = mp[16] ? MLOG2 : Sacc[rf][1][reg];
        float x2 = mp[32] ? MLOG2 : Sacc[rf][2][reg];
        float x3 = mp[48] ? MLOG2 : Sacc[rf][3][reg];
        float xm = fmaxf(fmaxf(x0,x1), fmaxf(x2,x3));
        float mo = mrow[rf][reg];
        float mn = fmaxf(mo, xm);
        float lo = lrow[rf][reg] * exp2f(mo - mn);
        lo += exp2f(x0-mn)+exp2f(x1-mn)+exp2f(x2-mn)+exp2f(x3-mn);
        mrow[rf][reg]=mn; lrow[rf][reg]=lo;
      }
    }

    // W += maskTile @ Vtile  (A = binary mask from global, B = VT from LDS)
    #pragma unroll
    for (int ksw=0; ksw<2; ++ksw){
      bf16x8 am[2];
      #pragma unroll
      for (int rf=0; rf<2; ++rf){
        const int* mp = maskb + (size_t)(rowbase + 16*rf + l16)*S_ + t0 + 32*ksw + lhi*8;
        int4 m0 = *(const int4*)mp;
        int4 m1 = *(const int4*)(mp+4);
        bf16x8 f;
        f[0] = m0.x ? (short)0x3F80 : (short)0;
        f[1] = m0.y ? (short)0x3F80 : (short)0;
        f[2] = m0.z ? (short)0x3F80 : (short)0;
        f[3] = m0.w ? (short)0x3F80 : (short)0;
        f[4] = m1.x ? (short)0x3F80 : (short)0;
        f[5] = m1.y ? (short)0x3F80 : (short)0;
        f[6] = m1.z ? (short)0x3F80 : (short)0;
        f[7] = m1.w ? (short)0x3F80 : (short)0;
        am[rf] = f;
      }
      #pragma unroll
      for (int dc=0; dc<8; ++dc){
        int d_l = 16*dc + l16;
        int cb = 64*ksw + lhi*16;
        bf16x8 bfr = *(const bf16x8*)(Vsm + d_l*128 + (cb ^ ((d_l&7)<<4)));
        Wacc[0][dc] = __builtin_amdgcn_mfma_f32_16x16x32_bf16(am[0], bfr, Wacc[0][dc], 0,0,0);
        Wacc[1][dc] = __builtin_amdgcn_mfma_f32_16x16x32_bf16(am[1], bfr, Wacc[1][dc], 0,0,0);
      }
    }
  }

  // final row-stat reduce across the 16-lane group, c = 2^(MLOG2-m)/l
  float cval[2][4];
  #pragma unroll
  for (int rf=0;rf<2;++rf){
    #pragma unroll
    for (int reg=0;reg<4;++reg){
      float m = mrow[rf][reg], l = lrow[rf][reg];
      #pragma unroll
      for (int off=1; off<16; off<<=1){
        float m2 = __shfl_xor(m, off);
        float l2 = __shfl_xor(l, off);
        float mn = fmaxf(m, m2);
        l = l*exp2f(m-mn) + l2*exp2f(m2-mn);
        m = mn;
      }
      float c = exp2f(MLOG2 - m) / l;
      cval[rf][reg] = c;
      if (l16 == 0){
        c_ws[(size_t)bh*S_ + rowbase + 16*rf + 4*lhi + reg] = c;
      }
    }
  }
  // out = c * W
  #pragma unroll
  for (int rf=0;rf<2;++rf){
    #pragma unroll
    for (int dc=0;dc<8;++dc){
      #pragma unroll
      for (int reg=0;reg<4;++reg){
        int srow = rowbase + 16*rf + 4*lhi + reg;
        outp[((size_t)bh*S_ + srow)*D_ + 16*dc + l16] = cval[rf][reg]*Wacc[rf][dc][reg];
      }
    }
  }
}

// ---- atten output: atten[b,h,s,:] = c[b,h,s] * mask[b,s,:] (mask read once per 16 heads) ----
__global__ void atten_kernel(const int* __restrict__ mask, const float* __restrict__ c_ws,
                             float* __restrict__ atten){
  int blk = blockIdx.x;            // B_*S_ = 4096 blocks
  int bq = blk >> 11;
  int s  = blk & 2047;
  __shared__ float csm[16];
  if (threadIdx.x < 16)
    csm[threadIdx.x] = c_ws[((size_t)(bq*H_ + threadIdx.x))*S_ + s];
  __syncthreads();
  const int4* mrow = (const int4*)(mask + ((size_t)bq*S_ + s)*S_);
  for (int i = threadIdx.x; i < S_/4; i += 256){
    int4 mv = mrow[i];
    float fx = mv.x ? 1.f : 0.f;
    float fy = mv.y ? 1.f : 0.f;
    float fz = mv.z ? 1.f : 0.f;
    float fw = mv.w ? 1.f : 0.f;
    #pragma unroll
    for (int h=0; h<H_; ++h){
      float c = csm[h];
      f32x4 o = { c*fx, c*fy, c*fz, c*fw };
      ((f32x4*)(atten + (((size_t)(bq*H_ + h)*S_ + s)*S_)))[i] = o;
    }
  }
}

extern "C" void kernel_launch(void* const* d_in, const int* in_sizes, int n_in,
                              void* d_out, int out_size, void* d_ws, size_t ws_size,
                              hipStream_t stream){
  const float* q = (const float*)d_in[0];
  const float* k = (const float*)d_in[1];
  const float* v = (const float*)d_in[2];
  const int* mask = (const int*)d_in[3];
  float* outp = (float*)d_out;
  float* atten = outp + (size_t)B_*H_*S_*D_;

  unsigned short* KB = (unsigned short*)d_ws;
  unsigned short* VT = KB + (size_t)B_*H_*S_*D_;
  float* c_ws = (float*)(VT + (size_t)B_*H_*S_*D_);

  hipLaunchKernelGGL(kconv_kernel,  dim3(8192), dim3(256), 0, stream, k, KB);
  hipLaunchKernelGGL(vtrans_kernel, dim3(2048), dim3(256), 0, stream, v, VT);
  hipLaunchKernelGGL(fused_kernel,  dim3(512),  dim3(256), 0, stream, q, mask, KB, VT, outp, c_ws);
  hipLaunchKernelGGL(atten_kernel,  dim3(4096), dim3(256), 0, stream, mask, c_ws, atten);
}

// Round 2
// 326.487 us; speedup vs baseline: 1.2131x; 1.2131x over previous
//
#include <hip/hip_runtime.h>
#include <stdint.h>

#define B_ 2
#define H_ 16
#define S_ 2048
#define D_ 128

typedef float f32x4 __attribute__((ext_vector_type(4)));
typedef short bf16x8 __attribute__((ext_vector_type(8)));
typedef unsigned short u16x4 __attribute__((ext_vector_type(4)));
typedef int i32x4 __attribute__((ext_vector_type(4)));

__device__ __forceinline__ unsigned short f2bf(float x){
  union { float f; uint32_t u; } c; c.f = x;
  uint32_t u = c.u;
  uint32_t r = (u + 0x7FFFu + ((u >> 16) & 1u)) >> 16;
  return (unsigned short)r;
}

// ---- prep: K fp32 -> bf16 (same layout) ----
__global__ void kconv_kernel(const float* __restrict__ k, unsigned short* __restrict__ KB){
  size_t i = (size_t)blockIdx.x * 256 + threadIdx.x;   // 2,097,152 float4s exactly
  f32x4 v = __builtin_nontemporal_load(&((const f32x4*)k)[i]);
  u16x4 o; o[0]=f2bf(v.x); o[1]=f2bf(v.y); o[2]=f2bf(v.z); o[3]=f2bf(v.w);
  __builtin_nontemporal_store(o, &((u16x4*)KB)[i]);
}

// ---- prep: V fp32 [bh][t][d] -> VT bf16 [bh][d][t] ----
__global__ void vtrans_kernel(const float* __restrict__ v, unsigned short* __restrict__ VT){
  __shared__ float tile[64][73];          // pad 73: col-reads spread over banks (was 16-way @72)
  int blk = blockIdx.x;                   // 2048 = 32 bh * 32 ttile * 2 dtile
  int bh = blk >> 6;
  int ts = (blk >> 1) & 31;
  int dsec = blk & 1;
  int t0 = ts*64, d0 = dsec*64;
  const float* vb = v + ((size_t)bh*S_ + t0)*D_ + d0;
  int tid = threadIdx.x;
  #pragma unroll
  for (int i=0;i<4;++i){
    int fi = i*256 + tid;                 // 1024 float4 per tile
    int r = fi >> 4;
    int c4 = (fi & 15) * 4;
    f32x4 val = __builtin_nontemporal_load((const f32x4*)(vb + (size_t)r*D_ + c4));
    tile[r][c4+0]=val.x; tile[r][c4+1]=val.y; tile[r][c4+2]=val.z; tile[r][c4+3]=val.w;
  }
  __syncthreads();
  unsigned short* ob = VT + ((size_t)bh*D_ + d0)*S_ + t0;
  #pragma unroll
  for (int i=0;i<4;++i){
    int ui = i*256 + tid;                 // 1024 ushort4 per tile
    int dr = ui >> 4;
    int tc = (ui & 15) * 4;
    u16x4 o;
    o[0] = f2bf(tile[tc+0][dr]);
    o[1] = f2bf(tile[tc+1][dr]);
    o[2] = f2bf(tile[tc+2][dr]);
    o[3] = f2bf(tile[tc+3][dr]);
    __builtin_nontemporal_store(o, (u16x4*)(ob + (size_t)dr*S_ + tc));
  }
}

// ---- main fused kernel: stats l + W = mask@V, out = W/l ----
__launch_bounds__(256, 2)
__global__ void fused_kernel(const float* __restrict__ q,
                             const int* __restrict__ mask,
                             const unsigned short* __restrict__ KB,
                             const unsigned short* __restrict__ VT,
                             float* __restrict__ outp,
                             float* __restrict__ c_ws)
{
  __shared__ unsigned char Ksm[64*256];    // [t][128 bf16], row-XOR-swizzled
  __shared__ unsigned char Vsm[128*128];   // [d][64 bf16],  row-XOR-swizzled
  const int tid = threadIdx.x;
  const int lane = tid & 63;
  const int w = tid >> 6;
  const int l16 = lane & 15;
  const int lhi = lane >> 4;

  const int blk = blockIdx.x;
  const int bh = blk >> 4;
  const int qt = blk & 15;
  const int b = bh >> 4;
  const int s0 = qt * 128;
  const int rowbase = s0 + 32*w;

  const float QS = 1.4426950408889634f / 11.313708498984761f;  // log2(e)/TEMP

  // Q fragments (2 rf x 4 ks), scaled into log2 domain
  bf16x8 qf[2][4];
  #pragma unroll
  for (int rf=0; rf<2; ++rf){
    const float* qp = q + ((size_t)bh*S_ + (rowbase + 16*rf + l16))*D_ + lhi*8;
    #pragma unroll
    for (int ks=0; ks<4; ++ks){
      f32x4 a0 = __builtin_nontemporal_load((const f32x4*)(qp + 32*ks));
      f32x4 a1 = __builtin_nontemporal_load((const f32x4*)(qp + 32*ks + 4));
      bf16x8 f;
      f[0]=(short)f2bf(a0.x*QS); f[1]=(short)f2bf(a0.y*QS);
      f[2]=(short)f2bf(a0.z*QS); f[3]=(short)f2bf(a0.w*QS);
      f[4]=(short)f2bf(a1.x*QS); f[5]=(short)f2bf(a1.y*QS);
      f[6]=(short)f2bf(a1.z*QS); f[7]=(short)f2bf(a1.w*QS);
      qf[rf][ks] = f;
    }
  }

  f32x4 Wacc[2][8];
  #pragma unroll
  for (int rf=0;rf<2;++rf)
    #pragma unroll
    for (int dc=0;dc<8;++dc){ f32x4 z = {0.f,0.f,0.f,0.f}; Wacc[rf][dc] = z; }
  float lrow[2][4];
  #pragma unroll
  for (int rf=0;rf<2;++rf)
    #pragma unroll
    for (int r=0;r<4;++r){ lrow[rf][r]=0.f; }

  const unsigned short* Kg = KB + (size_t)bh*S_*D_;
  const unsigned short* Vg = VT + (size_t)bh*D_*S_;
  const int* maskb = mask + (size_t)b*S_*S_;

  for (int it=0; it<32; ++it){
    const int t0 = it*64;
    __syncthreads();
    // stage K tile (64 rows x 256B) and VT tile (128 rows x 128B), swizzled
    {
      const unsigned char* src = (const unsigned char*)(Kg + (size_t)t0*D_);
      #pragma unroll
      for (int i=0;i<4;++i){
        int chunk = i*256 + tid;        // 1024 chunks of 16B
        int r = chunk >> 4;
        int cb = (chunk & 15) << 4;
        i32x4 val = *(const i32x4*)(src + (size_t)r*256 + cb);
        *(i32x4*)(Ksm + r*256 + (cb ^ ((r&7)<<4))) = val;
      }
      const unsigned char* vsrc = (const unsigned char*)(Vg + t0);
      #pragma unroll
      for (int i=0;i<4;++i){
        int chunk = i*256 + tid;        // 1024 chunks of 16B
        int r = chunk >> 3;             // 128 rows x 8 chunks
        int cb = (chunk & 7) << 4;
        i32x4 val = *(const i32x4*)(vsrc + (size_t)r*(S_*2) + cb);
        *(i32x4*)(Vsm + r*128 + (cb ^ ((r&7)<<4))) = val;
      }
    }
    __syncthreads();

    // preload this tile's stats-path mask dwords (hide L2 latency under MFMAs)
    int msk[2][4][4];                   // [rf][reg][cf]
    #pragma unroll
    for (int rf=0; rf<2; ++rf){
      #pragma unroll
      for (int reg=0; reg<4; ++reg){
        const int* mp = maskb + (size_t)(rowbase + 16*rf + 4*lhi + reg)*S_ + t0 + l16;
        msk[rf][reg][0]=mp[0]; msk[rf][reg][1]=mp[16]; msk[rf][reg][2]=mp[32]; msk[rf][reg][3]=mp[48];
      }
    }

    // QK^T -> S fragments (log2 domain)
    f32x4 Sacc[2][4];
    #pragma unroll
    for (int rf=0;rf<2;++rf)
      #pragma unroll
      for (int cf=0;cf<4;++cf){ f32x4 z = {0.f,0.f,0.f,0.f}; Sacc[rf][cf] = z; }
    #pragma unroll
    for (int cf=0; cf<4; ++cf){
      int t_l = 16*cf + l16;
      #pragma unroll
      for (int ks=0; ks<4; ++ks){
        int cb = 64*ks + lhi*16;
        bf16x8 bfr = *(const bf16x8*)(Ksm + t_l*256 + (cb ^ ((t_l&7)<<4)));
        Sacc[0][cf] = __builtin_amdgcn_mfma_f32_16x16x32_bf16(qf[0][ks], bfr, Sacc[0][cf], 0,0,0);
        Sacc[1][cf] = __builtin_amdgcn_mfma_f32_16x16x32_bf16(qf[1][ks], bfr, Sacc[1][cf], 0,0,0);
      }
    }

    // stats: no max needed (|score*log2e| <~ 17, fp32 sum safe).
    // masked -> exp2(0)=1.0 == exp(1e-9) in fp32
    #pragma unroll
    for (int rf=0; rf<2; ++rf){
      #pragma unroll
      for (int reg=0; reg<4; ++reg){
        float x0 = msk[rf][reg][0] ? 0.f : Sacc[rf][0][reg];
        float x1 = msk[rf][reg][1] ? 0.f : Sacc[rf][1][reg];
        float x2 = msk[rf][reg][2] ? 0.f : Sacc[rf][2][reg];
        float x3 = msk[rf][reg][3] ? 0.f : Sacc[rf][3][reg];
        float e0 = __builtin_amdgcn_exp2f(x0);
        float e1 = __builtin_amdgcn_exp2f(x1);
        float e2 = __builtin_amdgcn_exp2f(x2);
        float e3 = __builtin_amdgcn_exp2f(x3);
        lrow[rf][reg] += (e0+e1)+(e2+e3);
      }
    }

    // W += maskTile @ Vtile  (A = binary mask expanded to bf16 arithmetically)
    #pragma unroll
    for (int ksw=0; ksw<2; ++ksw){
      bf16x8 am[2];
      #pragma unroll
      for (int rf=0; rf<2; ++rf){
        const int* mp = maskb + (size_t)(rowbase + 16*rf + l16)*S_ + t0 + 32*ksw + lhi*8;
        i32x4 m0 = *(const i32x4*)mp;
        i32x4 m1 = *(const i32x4*)(mp+4);
        union { bf16x8 v; uint32_t u[4]; } pk;
        pk.u[0] = (uint32_t)(m0[0] | (m0[1]<<16)) * 0x3F80u;
        pk.u[1] = (uint32_t)(m0[2] | (m0[3]<<16)) * 0x3F80u;
        pk.u[2] = (uint32_t)(m1[0] | (m1[1]<<16)) * 0x3F80u;
        pk.u[3] = (uint32_t)(m1[2] | (m1[3]<<16)) * 0x3F80u;
        am[rf] = pk.v;
      }
      #pragma unroll
      for (int dc=0; dc<8; ++dc){
        int d_l = 16*dc + l16;
        int cb = 64*ksw + lhi*16;
        bf16x8 bfr = *(const bf16x8*)(Vsm + d_l*128 + (cb ^ ((d_l&7)<<4)));
        Wacc[0][dc] = __builtin_amdgcn_mfma_f32_16x16x32_bf16(am[0], bfr, Wacc[0][dc], 0,0,0);
        Wacc[1][dc] = __builtin_amdgcn_mfma_f32_16x16x32_bf16(am[1], bfr, Wacc[1][dc], 0,0,0);
      }
    }
  }

  // final row-sum across the 16-lane group, c = 1/l
  float cval[2][4];
  #pragma unroll
  for (int rf=0;rf<2;++rf){
    #pragma unroll
    for (int reg=0;reg<4;++reg){
      float l = lrow[rf][reg];
      l += __shfl_xor(l, 1);
      l += __shfl_xor(l, 2);
      l += __shfl_xor(l, 4);
      l += __shfl_xor(l, 8);
      float c = 1.0f / l;
      cval[rf][reg] = c;
      if (l16 == 0){
        c_ws[(size_t)bh*S_ + rowbase + 16*rf + 4*lhi + reg] = c;
      }
    }
  }
  // out = c * W
  #pragma unroll
  for (int rf=0;rf<2;++rf){
    #pragma unroll
    for (int dc=0;dc<8;++dc){
      #pragma unroll
      for (int reg=0;reg<4;++reg){
        int srow = rowbase + 16*rf + 4*lhi + reg;
        __builtin_nontemporal_store(cval[rf][reg]*Wacc[rf][dc][reg],
                                    &outp[((size_t)bh*S_ + srow)*D_ + 16*dc + l16]);
      }
    }
  }
}

// ---- atten output: atten[b,h,s,:] = c[b,h,s] * mask[b,s,:] (mask read once per 16 heads) ----
__global__ void atten_kernel(const int* __restrict__ mask, const float* __restrict__ c_ws,
                             float* __restrict__ atten){
  int blk = blockIdx.x;            // B_*S_ = 4096 blocks
  int bq = blk >> 11;
  int s  = blk & 2047;
  __shared__ float csm[16];
  if (threadIdx.x < 16)
    csm[threadIdx.x] = c_ws[((size_t)(bq*H_ + threadIdx.x))*S_ + s];
  __syncthreads();
  const i32x4* mrow = (const i32x4*)(mask + ((size_t)bq*S_ + s)*S_);
  for (int i = threadIdx.x; i < S_/4; i += 256){
    i32x4 mv = __builtin_nontemporal_load(&mrow[i]);
    float fx = mv[0] ? 1.f : 0.f;
    float fy = mv[1] ? 1.f : 0.f;
    float fz = mv[2] ? 1.f : 0.f;
    float fw = mv[3] ? 1.f : 0.f;
    #pragma unroll
    for (int h=0; h<H_; ++h){
      float c = csm[h];
      f32x4 o = { c*fx, c*fy, c*fz, c*fw };
      __builtin_nontemporal_store(o, ((f32x4*)(atten + (((size_t)(bq*H_ + h)*S_ + s)*S_))) + i);
    }
  }
}

extern "C" void kernel_launch(void* const* d_in, const int* in_sizes, int n_in,
                              void* d_out, int out_size, void* d_ws, size_t ws_size,
                              hipStream_t stream){
  const float* q = (const float*)d_in[0];
  const float* k = (const float*)d_in[1];
  const float* v = (const float*)d_in[2];
  const int* mask = (const int*)d_in[3];
  float* outp = (float*)d_out;
  float* atten = outp + (size_t)B_*H_*S_*D_;

  unsigned short* KB = (unsigned short*)d_ws;
  unsigned short* VT = KB + (size_t)B_*H_*S_*D_;
  float* c_ws = (float*)(VT + (size_t)B_*H_*S_*D_);

  hipLaunchKernelGGL(kconv_kernel,  dim3(8192), dim3(256), 0, stream, k, KB);
  hipLaunchKernelGGL(vtrans_kernel, dim3(2048), dim3(256), 0, stream, v, VT);
  hipLaunchKernelGGL(fused_kernel,  dim3(512),  dim3(256), 0, stream, q, mask, KB, VT, outp, c_ws);
  hipLaunchKernelGGL(atten_kernel,  dim3(4096), dim3(256), 0, stream, mask, c_ws, atten);
}